// Round 14
// baseline (120.395 us; speedup 1.0000x reference)
//
#include <hip/hip_runtime.h>

// ---------------------------------------------------------------------------
// MS Deformable Attention (Deformable-DETR), MI355X gfx950.
//   1. valueT = bf16( input_flatten @ W_val^T + b_val ) -> [n][h][pix][64]
//      (XCD-pinned 1D grid: 4 bn-blocks of one bm share one XCD's L2)
//   2. fused  = query @ [W_off;W_attn]^T + [b_off;b_attn]  [4000 x 384] f32
//   3. msout  = bilinear-sample(valueT, loc, softmax(logits)) -> bf16
//   4. out    = msout @ W_out^T + b_out    [4000 x 256] f32
// vs R13: cvt_k DELETED. f32 operands are reg-staged (load f32 -> regs early,
// v_cvt_pk_bf16_f32 + ds_write_b128 AFTER the compute phase covers latency).
// LDS stays bf16/64KB (2 blocks/CU) — avoids R12's f32-LDS occupancy collapse.
// sample_k + epilogues + grid mappings = R13 verbatim.
// ---------------------------------------------------------------------------

typedef __attribute__((ext_vector_type(4))) float f32x4;
typedef __attribute__((ext_vector_type(4))) unsigned int u32x4;
typedef __attribute__((ext_vector_type(8))) short bf16x8;
typedef __attribute__((ext_vector_type(4))) short bf16x4;

static __device__ __forceinline__ unsigned short f2bf(float f) {
    unsigned u = __builtin_bit_cast(unsigned, f);
    u += 0x7FFFu + ((u >> 16) & 1u);   // round-to-nearest-even
    return (unsigned short)(u >> 16);
}
static __device__ __forceinline__ float bflo(unsigned d) {
    return __builtin_bit_cast(float, d << 16);
}
static __device__ __forceinline__ float bfhi(unsigned d) {
    return __builtin_bit_cast(float, d & 0xffff0000u);
}
static __device__ __forceinline__ unsigned cvtpk(float lo, float hi) {
    unsigned r;
    asm("v_cvt_pk_bf16_f32 %0, %1, %2" : "=v"(r) : "v"(lo), "v"(hi));
    return r;
}
static __device__ __forceinline__ void gload_lds16(const void* g, void* l) {
    __builtin_amdgcn_global_load_lds(
        (const __attribute__((address_space(1))) void*)g,
        (__attribute__((address_space(3))) void*)l, 16, 0, 0);
}

// ---------------------------------------------------------------------------
// GEMM: C = A[M,K] @ B[N,K]^T + bias. BM=BN=128, BK=64, 4 waves 2x2, dbuf.
// LDS layout per phase (proven): A 16KB + B 16KB bf16; row r unit u stored at
// byte r*128 + (u^(r&7))*16; read side XOR-matches (R8-R13 proven).
// B always f32 reg-staged. MODE 1/2: A f32 reg-staged; MODE 0: A bf16 gload.
// MODE 0: C f32, bias[col].  MODE 2: dual bias + dual B src (rows>=256 -> B2).
// MODE 1: C bf16 -> valueT[n][h][pix][64], LDS-transpose epilogue, XCD grid.
// ---------------------------------------------------------------------------
template<int MODE>
__global__ __launch_bounds__(256)
void gemm_k(const void* __restrict__ Av, const void* __restrict__ Bv,
            const void* __restrict__ B2v,
            const float* __restrict__ bias, const float* __restrict__ bias2,
            void* __restrict__ Cv, int M, int N, int K) {
    __shared__ __align__(16) char smem[65536];   // 2 phases x (As+Bs)

    const int tid = threadIdx.x, lane = tid & 63, w = tid >> 6;
    const int wm = w >> 1, wn = w & 1;
    int bm, bn;
    if (MODE == 1) {
        const int bid = blockIdx.x;      // 0..1407; same-bm quad -> same XCD
        const int xcd = bid & 7;
        const int j   = bid >> 3;        // 0..175
        bm = xcd * 44 + (j >> 2);        // 8 XCDs x 44 bm-groups = 352
        bn = j & 3;
    } else {
        bm = blockIdx.x; bn = blockIdx.y;
    }

    // reg-staging map: thread covers row sr = tid>>1, units sh..sh+3 (16B units)
    const int sr = tid >> 1;
    const int sh = (tid & 1) << 2;
    int lofs[4];
#pragma unroll
    for (int i = 0; i < 4; i++)
        lofs[i] = sr * 128 + (((sh + i) ^ (sr & 7)) << 4);

    // A source
    const char* asrc = nullptr;
    const char* pa[4];
    if (MODE == 0) {   // bf16 A via gload_lds (proven)
        const int r8 = lane >> 3;
        const int cs16 = (((lane & 7) ^ r8) << 4);
#pragma unroll
        for (int j2 = 0; j2 < 4; j2++) {
            int ra = bm * 128 + j2 * 32 + w * 8 + r8; ra = ra < M ? ra : M - 1;
            pa[j2] = (const char*)Av + (size_t)ra * ((size_t)K * 2) + cs16;
        }
    } else {           // f32 A reg-staged
        int ra = bm * 128 + sr; ra = ra < M ? ra : M - 1;
        asrc = (const char*)Av + (size_t)ra * ((size_t)K * 4);
    }
    // B source (f32; MODE2 rows >=256 from B2)
    const char* bsrc;
    {
        int rb = bn * 128 + sr; rb = rb < N ? rb : N - 1;
        if (MODE == 2 && rb >= 256)
            bsrc = (const char*)B2v + (size_t)(rb - 256) * ((size_t)K * 4);
        else
            bsrc = (const char*)Bv + (size_t)rb * ((size_t)K * 4);
    }

    const int ldso = w << 10;
    const int NT = K >> 6;

    f32x4 ar[8], br[8];
    auto loadA = [&](int t) {
        if (MODE != 0) {
            const char* s = asrc + t * 256;
#pragma unroll
            for (int i = 0; i < 4; i++) {
                ar[2 * i]     = *(const f32x4*)(s + (sh + i) * 32);
                ar[2 * i + 1] = *(const f32x4*)(s + (sh + i) * 32 + 16);
            }
        } else {
            const int off = t << 7;
#pragma unroll
            for (int j2 = 0; j2 < 4; j2++)
                gload_lds16(pa[j2] + off, smem + ((t & 1) << 15) + j2 * 4096 + ldso);
        }
    };
    auto loadB = [&](int t) {
        const char* s = bsrc + t * 256;
#pragma unroll
        for (int i = 0; i < 4; i++) {
            br[2 * i]     = *(const f32x4*)(s + (sh + i) * 32);
            br[2 * i + 1] = *(const f32x4*)(s + (sh + i) * 32 + 16);
        }
    };
    auto writeA = [&](int t) {
        if (MODE != 0) {
            char* base = smem + ((t & 1) << 15);
#pragma unroll
            for (int i = 0; i < 4; i++) {
                u32x4 v = { cvtpk(ar[2*i][0], ar[2*i][1]), cvtpk(ar[2*i][2], ar[2*i][3]),
                            cvtpk(ar[2*i+1][0], ar[2*i+1][1]), cvtpk(ar[2*i+1][2], ar[2*i+1][3]) };
                *(u32x4*)(base + lofs[i]) = v;
            }
        }
    };
    auto writeB = [&](int t) {
        char* base = smem + ((t & 1) << 15) + 16384;
#pragma unroll
        for (int i = 0; i < 4; i++) {
            u32x4 v = { cvtpk(br[2*i][0], br[2*i][1]), cvtpk(br[2*i][2], br[2*i][3]),
                        cvtpk(br[2*i+1][0], br[2*i+1][1]), cvtpk(br[2*i+1][2], br[2*i+1][3]) };
            *(u32x4*)(base + lofs[i]) = v;
        }
    };

    // prologue: stage tile 0 into phase 0
    loadA(0); loadB(0); writeA(0); writeB(0);
    __syncthreads();

    f32x4 acc[4][4] = {};
    const int fr = lane & 15, fq = lane >> 4;
    const int k8b = fq << 4;
    const int swzR = (fr & 7) << 4;

    for (int t = 0; t < NT; ++t) {
        const int cur = (t & 1) << 15;
        if (t + 1 < NT) { loadA(t + 1); loadB(t + 1); }   // issue early, no wait
#pragma unroll
        for (int kk = 0; kk < 2; ++kk) {
            const int ko = ((kk << 6) + k8b) ^ swzR;
            bf16x8 af[4], bv[4];
#pragma unroll
            for (int m = 0; m < 4; m++)
                af[m] = *(const bf16x8*)(smem + cur + ((wm * 64 + m * 16 + fr) << 7) + ko);
#pragma unroll
            for (int nn = 0; nn < 4; nn++)
                bv[nn] = *(const bf16x8*)(smem + cur + 16384 + ((wn * 64 + nn * 16 + fr) << 7) + ko);
#pragma unroll
            for (int m = 0; m < 4; m++)
#pragma unroll
                for (int nn = 0; nn < 4; nn++)
                    acc[m][nn] = __builtin_amdgcn_mfma_f32_16x16x32_bf16(
                        af[m], bv[nn], acc[m][nn], 0, 0, 0);
        }
        if (t + 1 < NT) { writeA(t + 1); writeB(t + 1); } // latency now covered
        __syncthreads();
    }

    if (MODE != 1) {
        // C/D layout (m89-verified): col = lane&15, row = (lane>>4)*4 + j
        float* C = (float*)Cv;
        const int crow0 = bm * 128 + wm * 64 + fq * 4;
        const int ccol0 = bn * 128 + wn * 64 + fr;
#pragma unroll
        for (int m = 0; m < 4; m++) {
#pragma unroll
            for (int nn = 0; nn < 4; nn++) {
                const int col = ccol0 + nn * 16;
                const float bv2 = (MODE == 2 && col >= 256) ? bias2[col - 256]
                                                            : bias[col];
#pragma unroll
                for (int j = 0; j < 4; j++) {
                    const int row = crow0 + m * 16 + j;
                    if (row < M) C[(size_t)row * N + col] = acc[m][nn][j] + bv2;
                }
            }
        }
    } else {
        // per-wave LDS transpose epilogue (R7-proven)
        unsigned short* tile = (unsigned short*)smem + (size_t)w * (64 * 68);
        const int hh = bn * 2 + wn;                 // head, uniform per wave
        float bvs[4];
#pragma unroll
        for (int nn = 0; nn < 4; nn++) bvs[nn] = bias[hh * 64 + nn * 16 + fr];
#pragma unroll
        for (int m = 0; m < 4; m++)
#pragma unroll
            for (int nn = 0; nn < 4; nn++)
#pragma unroll
                for (int j = 0; j < 4; j++)
                    tile[(m * 16 + fq * 4 + j) * 68 + nn * 16 + fr] =
                        f2bf(acc[m][nn][j] + bvs[nn]);
        __syncthreads();
        unsigned short* VT = (unsigned short*)Cv;
        const int q4 = (lane & 15) * 4;
        const int prow = lane >> 4;                 // 0..3
#pragma unroll
        for (int it = 0; it < 16; ++it) {
            const int pl = it * 4 + prow;           // local pixel 0..63
            const int pixg = bm * 128 + wm * 64 + pl;
            if (pixg < M) {
                const int n = pixg / 11253;
                const int pix = pixg - n * 11253;
                bf16x4 v = *(const bf16x4*)&tile[pl * 68 + q4];
                *(bf16x4*)(VT + ((size_t)(n * 8 + hh) * 11253 + pix) * 64 + q4) = v;
            }
        }
    }
}

// ---------------------------------------------------------------------------
// Sampling (R10/R13-proven, verbatim): one wave per (n, q, h), XCD-pinned
// slices; scalar softmax; lane-parallel bilinear metadata; __shfl-broadcast
// gathers (indices stay in INT registers — no float-typed memory round trip).
// ---------------------------------------------------------------------------
__global__ __launch_bounds__(256)
void sample_k(const unsigned short* __restrict__ valueT, // [4][8][11253][64] bf16
              const float* __restrict__ refp,            // [4][1000][4][2]
              const float* __restrict__ fused,           // [4][1000][384]
              unsigned int* __restrict__ msout)          // [4][1000][256] dwords
{
    const int bid = blockIdx.x;          // 0..7999
    const int xcd = bid & 7;
    const int jj  = bid >> 3;            // 0..999
    const int sl  = jj / 250;            // 0..3
    const int qb  = jj - sl * 250;       // 0..249
    const int nh  = xcd * 4 + sl;        // 0..31 (= n*8 + h)
    const int q   = __builtin_amdgcn_readfirstlane(qb * 4 + (threadIdx.x >> 6));
    const int lane = threadIdx.x & 63;
    const int g    = lane >> 5;          // x-corner group (0: xb, 1: xb+1)
    const int n = nh >> 3, h = nh & 7;
    const int nq = n * 1000 + q;

    // softmax reduction over the 16 points (scalar, uniform loads)
    const float* lgp = fused + (size_t)nq * 384 + 256 + h * 16;
    float mx = lgp[0];
#pragma unroll
    for (int pp = 1; pp < 16; pp++) mx = fmaxf(mx, lgp[pp]);
    float s = 0.f;
#pragma unroll
    for (int pp = 0; pp < 16; pp++) s += __expf(lgp[pp] - mx);

    // per-point metadata on lane groups of 16 (lanes 0-31 are the sources)
    const int p  = lane & 15;
    const int lv = p >> 2;
    const int W  = lv == 0 ? 92 : lv == 1 ? 46 : lv == 2 ? 23 : 12;  // H == W
    const int st = lv == 0 ? 0 : lv == 1 ? 8464 : lv == 2 ? 10580 : 11109;

    const float a  = __expf(lgp[p] - mx) / s;
    const float rx = refp[(size_t)nq * 8 + lv * 2 + 0];
    const float ry = refp[(size_t)nq * 8 + lv * 2 + 1];
    const float ox = fused[(size_t)nq * 384 + h * 32 + p * 2 + 0];
    const float oy = fused[(size_t)nq * 384 + h * 32 + p * 2 + 1];

    const float x = rx * (float)W + ox - 0.5f;
    const float y = ry * (float)W + oy - 0.5f;
    const float xf = floorf(x), yf = floorf(y);
    const int x0 = (int)xf, y0 = (int)yf;
    const float lx = x - xf, ly = y - yf;
    const int xb = min(max(x0, 0), W - 2);
    const int yb = min(max(y0, 0), W - 2);
    const float wx0 = (xb     == x0) ? (1.f - lx) : ((xb     == x0 + 1) ? lx : 0.f);
    const float wx1 = (xb + 1 == x0) ? (1.f - lx) : ((xb + 1 == x0 + 1) ? lx : 0.f);
    const float wy0 = (yb     == y0) ? (1.f - ly) : ((yb     == y0 + 1) ? ly : 0.f);
    const float wy1 = (yb + 1 == y0) ? (1.f - ly) : ((yb + 1 == y0 + 1) ? ly : 0.f);
    const int idx0v = st + yb * W + xb;
    const int idx1v = idx0v + W;
    const float wxs = (lane & 16) ? wx1 : wx0;   // lane group picks its x-corner
    const float wav = a * wxs * wy0;
    const float wbv = a * wxs * wy1;

    const unsigned int* vb =
        (const unsigned int*)valueT + (size_t)nh * 11253 * 32;

    float acc0 = 0.f, acc1 = 0.f;
    const int srcb = g << 4;
#pragma unroll
    for (int pp = 0; pp < 16; pp++) {
        const int src = pp + srcb;           // lane pp (g=0) or pp+16 (g=1)
        const int   i0 = __shfl(idx0v, src);
        const int   i1 = __shfl(idx1v, src);
        const float w0 = __shfl(wav,   src);
        const float w1 = __shfl(wbv,   src);
        const unsigned d0 = vb[i0 * 32 + lane];   // lane>=32 reads pixel+1
        const unsigned d1 = vb[i1 * 32 + lane];
        acc0 = fmaf(w0, bflo(d0), acc0);
        acc1 = fmaf(w0, bfhi(d0), acc1);
        acc0 = fmaf(w1, bflo(d1), acc0);
        acc1 = fmaf(w1, bfhi(d1), acc1);
    }

    acc0 += __shfl(acc0, lane ^ 32);
    acc1 += __shfl(acc1, lane ^ 32);
    if (lane < 32) {
        const unsigned u = (unsigned)f2bf(acc0) | ((unsigned)f2bf(acc1) << 16);
        msout[(size_t)nq * 256 + h * 32 + (lane & 31)] = u;
    }
}

// ---------------------------------------------------------------------------
extern "C" void kernel_launch(void* const* d_in, const int* in_sizes, int n_in,
                              void* d_out, int out_size, void* d_ws, size_t ws_size,
                              hipStream_t stream) {
    (void)in_sizes; (void)n_in; (void)out_size; (void)ws_size;

    const float* query  = (const float*)d_in[0];
    const float* refp   = (const float*)d_in[1];
    const float* inpf   = (const float*)d_in[2];
    const float* W_off  = (const float*)d_in[5];
    const float* b_off  = (const float*)d_in[6];
    const float* W_attn = (const float*)d_in[7];
    const float* b_attn = (const float*)d_in[8];
    const float* W_val  = (const float*)d_in[9];
    const float* b_val  = (const float*)d_in[10];
    const float* W_out  = (const float*)d_in[11];
    const float* b_out  = (const float*)d_in[12];
    float* out = (float*)d_out;

    char* ws = (char*)d_ws;
    unsigned short* valueT = (unsigned short*)ws;            // 46,092,288 B
    float* fusedb = (float*)(ws + 46092288);                 //  6,144,000 B
    unsigned int* msoutu = (unsigned int*)(ws + 52236288);   //  4,096,000 B
    unsigned short* msoutb = (unsigned short*)msoutu;

    // 1. value projection (A=inpf f32, B=W_val f32) -> bf16, XCD-pinned grid
    gemm_k<1><<<1408, 256, 0, stream>>>(
        inpf, W_val, nullptr, b_val, nullptr, valueT, 45012, 512, 256);
    // 2. fused offsets+logits (A=query f32, B=[W_off|W_attn] f32) -> [4000x384]
    gemm_k<2><<<dim3(32, 3), 256, 0, stream>>>(
        query, W_off, W_attn, b_off, b_attn, fusedb, 4000, 384, 256);
    // 3. sampling (fused softmax), msout bf16
    sample_k<<<8000, 256, 0, stream>>>(valueT, refp, fusedb, msoutu);
    // 4. output projection (A=msout bf16, B=W_out f32)
    gemm_k<0><<<dim3(32, 2), 256, 0, stream>>>(
        msoutb, W_out, nullptr, b_out, nullptr, out, 4000, 256, 512);
}

// Round 16
// 86.742 us; speedup vs baseline: 1.3880x; 1.3880x over previous
//
#include <hip/hip_runtime.h>

// ---------------------------------------------------------------------------
// MS Deformable Attention (Deformable-DETR), MI355X gfx950.
//   0. cvt    : all f32 operands -> bf16 (one streaming kernel)
//   1. merged : 1504 blocks — bid<1408: valueT = bf16(inpf@W_val^T+b_val)
//      (XCD-pinned mapping, LDS-transpose epilogue); bid>=1408: fused =
//      query @ [W_off|W_attn]^T + biases [4000x384] f32.
//   2. msout  = bilinear-sample(valueT, loc, softmax(logits)) -> bf16
//      (R13 shfl metadata — table variants empirically banned: 4/4 failures)
//   3. out    = msout @ W_out^T + b_out    [4000 x 256] f32
// Single change vs R13 (93.6 us proven): the GEMM merge. Everything else
// byte-identical.
// ---------------------------------------------------------------------------

typedef __attribute__((ext_vector_type(4))) float f32x4;
typedef __attribute__((ext_vector_type(8))) short bf16x8;
typedef __attribute__((ext_vector_type(4))) short bf16x4;

static __device__ __forceinline__ unsigned short f2bf(float f) {
    unsigned u = __builtin_bit_cast(unsigned, f);
    u += 0x7FFFu + ((u >> 16) & 1u);   // round-to-nearest-even
    return (unsigned short)(u >> 16);
}
static __device__ __forceinline__ float bflo(unsigned d) {
    return __builtin_bit_cast(float, d << 16);
}
static __device__ __forceinline__ float bfhi(unsigned d) {
    return __builtin_bit_cast(float, d & 0xffff0000u);
}
static __device__ __forceinline__ void gload_lds16(const void* g, void* l) {
    __builtin_amdgcn_global_load_lds(
        (const __attribute__((address_space(1))) void*)g,
        (__attribute__((address_space(3))) void*)l, 16, 0, 0);
}

// ---------------------------------------------------------------------------
// f32 -> bf16 conversion of all operands into one packed buffer (R13 verbatim).
//   inpf 0 | query 11523072 | W_off 12547072 | W_attn 12612608
//   | W_val 12645376 | W_out 12776448 | total 12907520
// ---------------------------------------------------------------------------
__global__ __launch_bounds__(256)
void cvt_k(const float* __restrict__ s0, const float* __restrict__ s1,
           const float* __restrict__ s2, const float* __restrict__ s3,
           const float* __restrict__ s4, const float* __restrict__ s5,
           unsigned short* __restrict__ dst) {
    const size_t i8 = ((size_t)blockIdx.x * 256 + threadIdx.x) * 8;
    if (i8 >= 12907520u) return;
    const float* sp; size_t loc;
    if (i8 < 11523072u)      { sp = s0; loc = i8; }
    else if (i8 < 12547072u) { sp = s1; loc = i8 - 11523072u; }
    else if (i8 < 12612608u) { sp = s2; loc = i8 - 12547072u; }
    else if (i8 < 12645376u) { sp = s3; loc = i8 - 12612608u; }
    else if (i8 < 12776448u) { sp = s4; loc = i8 - 12645376u; }
    else                     { sp = s5; loc = i8 - 12776448u; }
    f32x4 a = *(const f32x4*)(sp + loc);
    f32x4 b = *(const f32x4*)(sp + loc + 4);
    bf16x8 r;
    r[0] = f2bf(a[0]); r[1] = f2bf(a[1]); r[2] = f2bf(a[2]); r[3] = f2bf(a[3]);
    r[4] = f2bf(b[0]); r[5] = f2bf(b[1]); r[6] = f2bf(b[2]); r[7] = f2bf(b[3]);
    *(bf16x8*)(dst + i8) = r;
}

// ---------------------------------------------------------------------------
// bf16 GEMM (R13-proven core): BM=BN=128, BK=64, 4 waves 2x2, dbuf LDS,
// global_load_lds staging with pre-XOR'd source, one __syncthreads/iter.
// MODE 0: out projection — C f32 [M,N], bias[col], 2D grid.
// MODE 3: merged — bid<1408: value path (A/B/bias/Cv; XCD-pinned mapping,
//         LDS-transpose epilogue); bid>=1408: fused path (A2/B2, dual bias
//         bias2/bias3, C=Cv2, M=4000 N=384).
// All operand row strides equal K (value/fused: 256; out: 512).
// ---------------------------------------------------------------------------
template<int MODE>
__global__ __launch_bounds__(256)
void gemm_bf16_tn(const unsigned short* __restrict__ A,
                  const unsigned short* __restrict__ B,
                  const unsigned short* __restrict__ A2,
                  const unsigned short* __restrict__ B2,
                  const float* __restrict__ bias, const float* __restrict__ bias2,
                  const float* __restrict__ bias3,
                  void* __restrict__ Cv, void* __restrict__ Cv2,
                  int M, int N, int K) {
    __shared__ __align__(16) char smem[65536];   // 2 phases x (As+Bs)

    const int tid = threadIdx.x, lane = tid & 63, w = tid >> 6;
    const int wm = w >> 1, wn = w & 1;

    const unsigned short* Ap = A;
    const unsigned short* Bp = B;
    bool vmode = false;
    int bm, bn;
    if (MODE == 3) {
        const int bid = blockIdx.x;
        if (bid < 1408) {                // value path (R13 MODE1 mapping)
            vmode = true;
            const int xcd = bid & 7;
            const int j   = bid >> 3;    // 0..175
            bm = xcd * 44 + (j >> 2);    // 8 XCDs x 44 groups = 352
            bn = j & 3;
        } else {                         // fused path (R13 MODE2, linearized)
            const int r = bid - 1408;    // 0..95
            bm = r & 31; bn = r >> 5;    // 32 x 3
            Ap = A2; Bp = B2;
            M = 4000; N = 384;
        }
    } else {
        bm = blockIdx.x; bn = blockIdx.y;
    }

    // staging map (proven): LDS byte (j*4096 + w*1024 + lane*16) ->
    // row j*32+w*8+(lane>>3); source 16B-block (lane&7) ^ (row&7).
    const int r8 = lane >> 3;
    const int colsrc = (((lane & 7) ^ r8) << 4);
    const char* pa[4]; const char* pb[4];
#pragma unroll
    for (int j = 0; j < 4; j++) {
        int ra = bm * 128 + j * 32 + w * 8 + r8; ra = ra < M ? ra : M - 1;
        int rb = bn * 128 + j * 32 + w * 8 + r8; rb = rb < N ? rb : N - 1;
        pa[j] = (const char*)Ap + (size_t)ra * ((size_t)K * 2) + colsrc;
        pb[j] = (const char*)Bp + (size_t)rb * ((size_t)K * 2) + colsrc;
    }
    const int ldso = w << 10;
    const int NT = K >> 6;

    f32x4 acc[4][4] = {};
    const int fr = lane & 15, fq = lane >> 4;
    const int k8b = fq << 4;
    const int swzR = (fr & 7) << 4;

#pragma unroll
    for (int j = 0; j < 4; j++) {
        gload_lds16(pa[j], smem + j * 4096 + ldso);
        gload_lds16(pb[j], smem + 16384 + j * 4096 + ldso);
    }
    __syncthreads();   // tile 0 visible

    for (int t = 0; t < NT; ++t) {
        const int cur = (t & 1) << 15;
        if (t + 1 < NT) {
            const int nxt = ((t + 1) & 1) << 15;
            const int off = (t + 1) << 7;
#pragma unroll
            for (int j = 0; j < 4; j++) {
                gload_lds16(pa[j] + off, smem + nxt + j * 4096 + ldso);
                gload_lds16(pb[j] + off, smem + nxt + 16384 + j * 4096 + ldso);
            }
        }
#pragma unroll
        for (int kk = 0; kk < 2; ++kk) {
            const int ko = ((kk << 6) + k8b) ^ swzR;
            bf16x8 af[4], bv[4];
#pragma unroll
            for (int m = 0; m < 4; m++)
                af[m] = *(const bf16x8*)(smem + cur + ((wm * 64 + m * 16 + fr) << 7) + ko);
#pragma unroll
            for (int nn = 0; nn < 4; nn++)
                bv[nn] = *(const bf16x8*)(smem + cur + 16384 + ((wn * 64 + nn * 16 + fr) << 7) + ko);
#pragma unroll
            for (int m = 0; m < 4; m++)
#pragma unroll
                for (int nn = 0; nn < 4; nn++)
                    acc[m][nn] = __builtin_amdgcn_mfma_f32_16x16x32_bf16(
                        af[m], bv[nn], acc[m][nn], 0, 0, 0);
        }
        __syncthreads();
    }

    if (MODE == 0 || !vmode) {
        // f32 row-major epilogue; fused path: dual bias (col>=256 -> bias3)
        float* C = (MODE == 3) ? (float*)Cv2 : (float*)Cv;
        const float* b1 = (MODE == 3) ? bias2 : bias;
        const int crow0 = bm * 128 + wm * 64 + fq * 4;
        const int ccol0 = bn * 128 + wn * 64 + fr;
#pragma unroll
        for (int m = 0; m < 4; m++) {
#pragma unroll
            for (int nn = 0; nn < 4; nn++) {
                const int col = ccol0 + nn * 16;
                const float bv2 = (MODE == 3 && col >= 256) ? bias3[col - 256]
                                                            : b1[col];
#pragma unroll
                for (int j = 0; j < 4; j++) {
                    const int row = crow0 + m * 16 + j;
                    if (row < M) C[(size_t)row * N + col] = acc[m][nn][j] + bv2;
                }
            }
        }
    } else {
        // per-wave LDS transpose epilogue (R7-proven) -> valueT
        unsigned short* tile = (unsigned short*)smem + (size_t)w * (64 * 68);
        const int hh = bn * 2 + wn;                 // head, uniform per wave
        float bvs[4];
#pragma unroll
        for (int nn = 0; nn < 4; nn++) bvs[nn] = bias[hh * 64 + nn * 16 + fr];
#pragma unroll
        for (int m = 0; m < 4; m++)
#pragma unroll
            for (int nn = 0; nn < 4; nn++)
#pragma unroll
                for (int j = 0; j < 4; j++)
                    tile[(m * 16 + fq * 4 + j) * 68 + nn * 16 + fr] =
                        f2bf(acc[m][nn][j] + bvs[nn]);
        __syncthreads();
        unsigned short* VT = (unsigned short*)Cv;
        const int q4 = (lane & 15) * 4;
        const int prow = lane >> 4;                 // 0..3
#pragma unroll
        for (int it = 0; it < 16; ++it) {
            const int pl = it * 4 + prow;           // local pixel 0..63
            const int pixg = bm * 128 + wm * 64 + pl;
            if (pixg < M) {
                const int n = pixg / 11253;
                const int pix = pixg - n * 11253;
                bf16x4 v = *(const bf16x4*)&tile[pl * 68 + q4];
                *(bf16x4*)(VT + ((size_t)(n * 8 + hh) * 11253 + pix) * 64 + q4) = v;
            }
        }
    }
}

// ---------------------------------------------------------------------------
// Sampling (R13 verbatim — shfl metadata, the only proven-correct transport):
// one wave per (n, q, h), XCD-pinned slices; scalar softmax; lane-parallel
// bilinear metadata; __shfl-broadcast gathers (indices stay in INT registers).
// ---------------------------------------------------------------------------
__global__ __launch_bounds__(256)
void sample_k(const unsigned short* __restrict__ valueT, // [4][8][11253][64] bf16
              const float* __restrict__ refp,            // [4][1000][4][2]
              const float* __restrict__ fused,           // [4][1000][384]
              unsigned int* __restrict__ msout)          // [4][1000][256] dwords
{
    const int bid = blockIdx.x;          // 0..7999
    const int xcd = bid & 7;
    const int jj  = bid >> 3;            // 0..999
    const int sl  = jj / 250;            // 0..3
    const int qb  = jj - sl * 250;       // 0..249
    const int nh  = xcd * 4 + sl;        // 0..31 (= n*8 + h)
    const int q   = __builtin_amdgcn_readfirstlane(qb * 4 + (threadIdx.x >> 6));
    const int lane = threadIdx.x & 63;
    const int g    = lane >> 5;          // x-corner group (0: xb, 1: xb+1)
    const int n = nh >> 3, h = nh & 7;
    const int nq = n * 1000 + q;

    // softmax reduction over the 16 points (scalar, uniform loads)
    const float* lgp = fused + (size_t)nq * 384 + 256 + h * 16;
    float mx = lgp[0];
#pragma unroll
    for (int pp = 1; pp < 16; pp++) mx = fmaxf(mx, lgp[pp]);
    float s = 0.f;
#pragma unroll
    for (int pp = 0; pp < 16; pp++) s += __expf(lgp[pp] - mx);

    // per-point metadata on lane groups of 16 (lanes 0-31 are the sources)
    const int p  = lane & 15;
    const int lv = p >> 2;
    const int W  = lv == 0 ? 92 : lv == 1 ? 46 : lv == 2 ? 23 : 12;  // H == W
    const int st = lv == 0 ? 0 : lv == 1 ? 8464 : lv == 2 ? 10580 : 11109;

    const float a  = __expf(lgp[p] - mx) / s;
    const float rx = refp[(size_t)nq * 8 + lv * 2 + 0];
    const float ry = refp[(size_t)nq * 8 + lv * 2 + 1];
    const float ox = fused[(size_t)nq * 384 + h * 32 + p * 2 + 0];
    const float oy = fused[(size_t)nq * 384 + h * 32 + p * 2 + 1];

    const float x = rx * (float)W + ox - 0.5f;
    const float y = ry * (float)W + oy - 0.5f;
    const float xf = floorf(x), yf = floorf(y);
    const int x0 = (int)xf, y0 = (int)yf;
    const float lx = x - xf, ly = y - yf;
    const int xb = min(max(x0, 0), W - 2);
    const int yb = min(max(y0, 0), W - 2);
    const float wx0 = (xb     == x0) ? (1.f - lx) : ((xb     == x0 + 1) ? lx : 0.f);
    const float wx1 = (xb + 1 == x0) ? (1.f - lx) : ((xb + 1 == x0 + 1) ? lx : 0.f);
    const float wy0 = (yb     == y0) ? (1.f - ly) : ((yb     == y0 + 1) ? ly : 0.f);
    const float wy1 = (yb + 1 == y0) ? (1.f - ly) : ((yb + 1 == y0 + 1) ? ly : 0.f);
    const int idx0v = st + yb * W + xb;
    const int idx1v = idx0v + W;
    const float wxs = (lane & 16) ? wx1 : wx0;   // lane group picks its x-corner
    const float wav = a * wxs * wy0;
    const float wbv = a * wxs * wy1;

    const unsigned int* vb =
        (const unsigned int*)valueT + (size_t)nh * 11253 * 32;

    float acc0 = 0.f, acc1 = 0.f;
    const int srcb = g << 4;
#pragma unroll
    for (int pp = 0; pp < 16; pp++) {
        const int src = pp + srcb;           // lane pp (g=0) or pp+16 (g=1)
        const int   i0 = __shfl(idx0v, src);
        const int   i1 = __shfl(idx1v, src);
        const float w0 = __shfl(wav,   src);
        const float w1 = __shfl(wbv,   src);
        const unsigned d0 = vb[i0 * 32 + lane];   // lane>=32 reads pixel+1
        const unsigned d1 = vb[i1 * 32 + lane];
        acc0 = fmaf(w0, bflo(d0), acc0);
        acc1 = fmaf(w0, bfhi(d0), acc1);
        acc0 = fmaf(w1, bflo(d1), acc0);
        acc1 = fmaf(w1, bfhi(d1), acc1);
    }

    acc0 += __shfl(acc0, lane ^ 32);
    acc1 += __shfl(acc1, lane ^ 32);
    if (lane < 32) {
        const unsigned u = (unsigned)f2bf(acc0) | ((unsigned)f2bf(acc1) << 16);
        msout[(size_t)nq * 256 + h * 32 + (lane & 31)] = u;
    }
}

// ---------------------------------------------------------------------------
extern "C" void kernel_launch(void* const* d_in, const int* in_sizes, int n_in,
                              void* d_out, int out_size, void* d_ws, size_t ws_size,
                              hipStream_t stream) {
    (void)in_sizes; (void)n_in; (void)out_size; (void)ws_size;

    const float* query  = (const float*)d_in[0];
    const float* refp   = (const float*)d_in[1];
    const float* inpf   = (const float*)d_in[2];
    const float* W_off  = (const float*)d_in[5];
    const float* b_off  = (const float*)d_in[6];
    const float* W_attn = (const float*)d_in[7];
    const float* b_attn = (const float*)d_in[8];
    const float* W_val  = (const float*)d_in[9];
    const float* b_val  = (const float*)d_in[10];
    const float* W_out  = (const float*)d_in[11];
    const float* b_out  = (const float*)d_in[12];
    float* out = (float*)d_out;

    char* ws = (char*)d_ws;
    unsigned short* bf = (unsigned short*)ws;                    // 25,815,040 B
    unsigned short* inpfb   = bf;
    unsigned short* queryb  = bf + 11523072;
    unsigned short* W_offb  = bf + 12547072;   // [W_off;W_attn] = [384 x 256]
    unsigned short* W_valb  = bf + 12645376;
    unsigned short* W_outb  = bf + 12776448;
    unsigned short* valueT  = (unsigned short*)(ws + 25815040);  // 46,092,288 B
    float* fusedb = (float*)(ws + 71907328);                     //  6,144,000 B
    unsigned int* msoutu = (unsigned int*)(ws + 78051328);       //  4,096,000 B
    unsigned short* msoutb = (unsigned short*)msoutu;

    // 0. convert everything to bf16
    cvt_k<<<6303, 256, 0, stream>>>(inpf, query, W_off, W_attn, W_val, W_out, bf);
    // 1. merged: value projection (1408 blocks) + fused off/logits (96 blocks)
    gemm_bf16_tn<3><<<1504, 256, 0, stream>>>(
        inpfb, W_valb, queryb, W_offb, b_val, b_off, b_attn,
        valueT, fusedb, 45012, 512, 256);
    // 2. sampling (fused softmax), msout bf16
    sample_k<<<8000, 256, 0, stream>>>(valueT, refp, fusedb, msoutu);
    // 3. output projection
    gemm_bf16_tn<0><<<dim3(32, 2), 256, 0, stream>>>(
        msoutb, W_outb, nullptr, nullptr, b_out, nullptr, nullptr,
        out, nullptr, 4000, 256, 512);
}

// Round 17
// 83.730 us; speedup vs baseline: 1.4379x; 1.0360x over previous
//
#include <hip/hip_runtime.h>

// ---------------------------------------------------------------------------
// MS Deformable Attention (Deformable-DETR), MI355X gfx950.
//   0. cvt    : all f32 operands -> bf16 (one streaming kernel)
//   1. merged : 1504 blocks — bid<1408: valueT = bf16(inpf@W_val^T+b_val)
//      (XCD-pinned mapping, LDS-transpose epilogue); bid>=1408: fused =
//      query @ [W_off|W_attn]^T + biases [4000x384] f32.
//   2. msout  = bilinear-sample(valueT, loc, softmax(logits)) -> bf16
//      (shfl metadata transport — proven 6/6; softmax now 16-group shfl-reduce;
//       i1 shfl eliminated via compile-time level width)
//   3. out    = msout @ W_out^T + b_out    [4000 x 256] f32
// vs R16 (86.7 us proven): only the inside of sample_k changed.
// ---------------------------------------------------------------------------

typedef __attribute__((ext_vector_type(4))) float f32x4;
typedef __attribute__((ext_vector_type(8))) short bf16x8;
typedef __attribute__((ext_vector_type(4))) short bf16x4;

static __device__ __forceinline__ unsigned short f2bf(float f) {
    unsigned u = __builtin_bit_cast(unsigned, f);
    u += 0x7FFFu + ((u >> 16) & 1u);   // round-to-nearest-even
    return (unsigned short)(u >> 16);
}
static __device__ __forceinline__ float bflo(unsigned d) {
    return __builtin_bit_cast(float, d << 16);
}
static __device__ __forceinline__ float bfhi(unsigned d) {
    return __builtin_bit_cast(float, d & 0xffff0000u);
}
static __device__ __forceinline__ void gload_lds16(const void* g, void* l) {
    __builtin_amdgcn_global_load_lds(
        (const __attribute__((address_space(1))) void*)g,
        (__attribute__((address_space(3))) void*)l, 16, 0, 0);
}

// ---------------------------------------------------------------------------
// f32 -> bf16 conversion of all operands into one packed buffer (proven).
//   inpf 0 | query 11523072 | W_off 12547072 | W_attn 12612608
//   | W_val 12645376 | W_out 12776448 | total 12907520
// ---------------------------------------------------------------------------
__global__ __launch_bounds__(256)
void cvt_k(const float* __restrict__ s0, const float* __restrict__ s1,
           const float* __restrict__ s2, const float* __restrict__ s3,
           const float* __restrict__ s4, const float* __restrict__ s5,
           unsigned short* __restrict__ dst) {
    const size_t i8 = ((size_t)blockIdx.x * 256 + threadIdx.x) * 8;
    if (i8 >= 12907520u) return;
    const float* sp; size_t loc;
    if (i8 < 11523072u)      { sp = s0; loc = i8; }
    else if (i8 < 12547072u) { sp = s1; loc = i8 - 11523072u; }
    else if (i8 < 12612608u) { sp = s2; loc = i8 - 12547072u; }
    else if (i8 < 12645376u) { sp = s3; loc = i8 - 12612608u; }
    else if (i8 < 12776448u) { sp = s4; loc = i8 - 12645376u; }
    else                     { sp = s5; loc = i8 - 12776448u; }
    f32x4 a = *(const f32x4*)(sp + loc);
    f32x4 b = *(const f32x4*)(sp + loc + 4);
    bf16x8 r;
    r[0] = f2bf(a[0]); r[1] = f2bf(a[1]); r[2] = f2bf(a[2]); r[3] = f2bf(a[3]);
    r[4] = f2bf(b[0]); r[5] = f2bf(b[1]); r[6] = f2bf(b[2]); r[7] = f2bf(b[3]);
    *(bf16x8*)(dst + i8) = r;
}

// ---------------------------------------------------------------------------
// bf16 GEMM (R16-proven): BM=BN=128, BK=64, 4 waves 2x2, dbuf LDS,
// global_load_lds staging with pre-XOR'd source, one __syncthreads/iter.
// MODE 0: out projection — C f32 [M,N], bias[col], 2D grid.
// MODE 3: merged — bid<1408: value path (XCD-pinned, LDS-transpose epilogue);
//         bid>=1408: fused path (A2/B2, dual bias, C=Cv2, M=4000 N=384).
// ---------------------------------------------------------------------------
template<int MODE>
__global__ __launch_bounds__(256)
void gemm_bf16_tn(const unsigned short* __restrict__ A,
                  const unsigned short* __restrict__ B,
                  const unsigned short* __restrict__ A2,
                  const unsigned short* __restrict__ B2,
                  const float* __restrict__ bias, const float* __restrict__ bias2,
                  const float* __restrict__ bias3,
                  void* __restrict__ Cv, void* __restrict__ Cv2,
                  int M, int N, int K) {
    __shared__ __align__(16) char smem[65536];   // 2 phases x (As+Bs)

    const int tid = threadIdx.x, lane = tid & 63, w = tid >> 6;
    const int wm = w >> 1, wn = w & 1;

    const unsigned short* Ap = A;
    const unsigned short* Bp = B;
    bool vmode = false;
    int bm, bn;
    if (MODE == 3) {
        const int bid = blockIdx.x;
        if (bid < 1408) {                // value path
            vmode = true;
            const int xcd = bid & 7;
            const int j   = bid >> 3;    // 0..175
            bm = xcd * 44 + (j >> 2);    // 8 XCDs x 44 groups = 352
            bn = j & 3;
        } else {                         // fused path
            const int r = bid - 1408;    // 0..95
            bm = r & 31; bn = r >> 5;    // 32 x 3
            Ap = A2; Bp = B2;
            M = 4000; N = 384;
        }
    } else {
        bm = blockIdx.x; bn = blockIdx.y;
    }

    const int r8 = lane >> 3;
    const int colsrc = (((lane & 7) ^ r8) << 4);
    const char* pa[4]; const char* pb[4];
#pragma unroll
    for (int j = 0; j < 4; j++) {
        int ra = bm * 128 + j * 32 + w * 8 + r8; ra = ra < M ? ra : M - 1;
        int rb = bn * 128 + j * 32 + w * 8 + r8; rb = rb < N ? rb : N - 1;
        pa[j] = (const char*)Ap + (size_t)ra * ((size_t)K * 2) + colsrc;
        pb[j] = (const char*)Bp + (size_t)rb * ((size_t)K * 2) + colsrc;
    }
    const int ldso = w << 10;
    const int NT = K >> 6;

    f32x4 acc[4][4] = {};
    const int fr = lane & 15, fq = lane >> 4;
    const int k8b = fq << 4;
    const int swzR = (fr & 7) << 4;

#pragma unroll
    for (int j = 0; j < 4; j++) {
        gload_lds16(pa[j], smem + j * 4096 + ldso);
        gload_lds16(pb[j], smem + 16384 + j * 4096 + ldso);
    }
    __syncthreads();   // tile 0 visible

    for (int t = 0; t < NT; ++t) {
        const int cur = (t & 1) << 15;
        if (t + 1 < NT) {
            const int nxt = ((t + 1) & 1) << 15;
            const int off = (t + 1) << 7;
#pragma unroll
            for (int j = 0; j < 4; j++) {
                gload_lds16(pa[j] + off, smem + nxt + j * 4096 + ldso);
                gload_lds16(pb[j] + off, smem + nxt + 16384 + j * 4096 + ldso);
            }
        }
#pragma unroll
        for (int kk = 0; kk < 2; ++kk) {
            const int ko = ((kk << 6) + k8b) ^ swzR;
            bf16x8 af[4], bv[4];
#pragma unroll
            for (int m = 0; m < 4; m++)
                af[m] = *(const bf16x8*)(smem + cur + ((wm * 64 + m * 16 + fr) << 7) + ko);
#pragma unroll
            for (int nn = 0; nn < 4; nn++)
                bv[nn] = *(const bf16x8*)(smem + cur + 16384 + ((wn * 64 + nn * 16 + fr) << 7) + ko);
#pragma unroll
            for (int m = 0; m < 4; m++)
#pragma unroll
                for (int nn = 0; nn < 4; nn++)
                    acc[m][nn] = __builtin_amdgcn_mfma_f32_16x16x32_bf16(
                        af[m], bv[nn], acc[m][nn], 0, 0, 0);
        }
        __syncthreads();
    }

    if (MODE == 0 || !vmode) {
        float* C = (MODE == 3) ? (float*)Cv2 : (float*)Cv;
        const float* b1 = (MODE == 3) ? bias2 : bias;
        const int crow0 = bm * 128 + wm * 64 + fq * 4;
        const int ccol0 = bn * 128 + wn * 64 + fr;
#pragma unroll
        for (int m = 0; m < 4; m++) {
#pragma unroll
            for (int nn = 0; nn < 4; nn++) {
                const int col = ccol0 + nn * 16;
                const float bv2 = (MODE == 3 && col >= 256) ? bias3[col - 256]
                                                            : b1[col];
#pragma unroll
                for (int j = 0; j < 4; j++) {
                    const int row = crow0 + m * 16 + j;
                    if (row < M) C[(size_t)row * N + col] = acc[m][nn][j] + bv2;
                }
            }
        }
    } else {
        // per-wave LDS transpose epilogue (proven) -> valueT
        unsigned short* tile = (unsigned short*)smem + (size_t)w * (64 * 68);
        const int hh = bn * 2 + wn;                 // head, uniform per wave
        float bvs[4];
#pragma unroll
        for (int nn = 0; nn < 4; nn++) bvs[nn] = bias[hh * 64 + nn * 16 + fr];
#pragma unroll
        for (int m = 0; m < 4; m++)
#pragma unroll
            for (int nn = 0; nn < 4; nn++)
#pragma unroll
                for (int j = 0; j < 4; j++)
                    tile[(m * 16 + fq * 4 + j) * 68 + nn * 16 + fr] =
                        f2bf(acc[m][nn][j] + bvs[nn]);
        __syncthreads();
        unsigned short* VT = (unsigned short*)Cv;
        const int q4 = (lane & 15) * 4;
        const int prow = lane >> 4;                 // 0..3
#pragma unroll
        for (int it = 0; it < 16; ++it) {
            const int pl = it * 4 + prow;           // local pixel 0..63
            const int pixg = bm * 128 + wm * 64 + pl;
            if (pixg < M) {
                const int n = pixg / 11253;
                const int pix = pixg - n * 11253;
                bf16x4 v = *(const bf16x4*)&tile[pl * 68 + q4];
                *(bf16x4*)(VT + ((size_t)(n * 8 + hh) * 11253 + pix) * 64 + q4) = v;
            }
        }
    }
}

// ---------------------------------------------------------------------------
// Sampling: one wave per (n, q, h), XCD-pinned slices (proven mapping).
// Softmax: 16-lane-group shfl_xor reduce (1 exp/lane instead of 16 wave-wide).
// Lane-parallel bilinear metadata; __shfl-broadcast gathers (3 shfls/point —
// i1 = i0 + W with W compile-time per unrolled point index).
// ---------------------------------------------------------------------------
__global__ __launch_bounds__(256)
void sample_k(const unsigned short* __restrict__ valueT, // [4][8][11253][64] bf16
              const float* __restrict__ refp,            // [4][1000][4][2]
              const float* __restrict__ fused,           // [4][1000][384]
              unsigned int* __restrict__ msout)          // [4][1000][256] dwords
{
    const int bid = blockIdx.x;          // 0..7999
    const int xcd = bid & 7;
    const int jj  = bid >> 3;            // 0..999
    const int sl  = jj / 250;            // 0..3
    const int qb  = jj - sl * 250;       // 0..249
    const int nh  = xcd * 4 + sl;        // 0..31 (= n*8 + h)
    const int q   = __builtin_amdgcn_readfirstlane(qb * 4 + (threadIdx.x >> 6));
    const int lane = threadIdx.x & 63;
    const int g    = lane >> 5;          // x-corner group (0: xb, 1: xb+1)
    const int n = nh >> 3, h = nh & 7;
    const int nq = n * 1000 + q;

    // per-point metadata on lane groups of 16 (lanes 0-31 are the sources)
    const int p  = lane & 15;
    const int lv = p >> 2;
    const int W  = lv == 0 ? 92 : lv == 1 ? 46 : lv == 2 ? 23 : 12;  // H == W
    const int st = lv == 0 ? 0 : lv == 1 ? 8464 : lv == 2 ? 10580 : 11109;

    // softmax over the 16 points: group-parallel shfl_xor reduction
    // (masks 1,2,4,8 stay within each 16-lane group; all groups identical)
    const float lg = fused[(size_t)nq * 384 + 256 + h * 16 + p];
    float mx = lg;
#pragma unroll
    for (int sft = 1; sft < 16; sft <<= 1) mx = fmaxf(mx, __shfl_xor(mx, sft));
    const float e = __expf(lg - mx);
    float sum = e;
#pragma unroll
    for (int sft = 1; sft < 16; sft <<= 1) sum += __shfl_xor(sum, sft);
    const float a = e / sum;

    const float rx = refp[(size_t)nq * 8 + lv * 2 + 0];
    const float ry = refp[(size_t)nq * 8 + lv * 2 + 1];
    const float ox = fused[(size_t)nq * 384 + h * 32 + p * 2 + 0];
    const float oy = fused[(size_t)nq * 384 + h * 32 + p * 2 + 1];

    const float x = rx * (float)W + ox - 0.5f;
    const float y = ry * (float)W + oy - 0.5f;
    const float xf = floorf(x), yf = floorf(y);
    const int x0 = (int)xf, y0 = (int)yf;
    const float lx = x - xf, ly = y - yf;
    const int xb = min(max(x0, 0), W - 2);
    const int yb = min(max(y0, 0), W - 2);
    const float wx0 = (xb     == x0) ? (1.f - lx) : ((xb     == x0 + 1) ? lx : 0.f);
    const float wx1 = (xb + 1 == x0) ? (1.f - lx) : ((xb + 1 == x0 + 1) ? lx : 0.f);
    const float wy0 = (yb     == y0) ? (1.f - ly) : ((yb     == y0 + 1) ? ly : 0.f);
    const float wy1 = (yb + 1 == y0) ? (1.f - ly) : ((yb + 1 == y0 + 1) ? ly : 0.f);
    const int idx0v = st + yb * W + xb;
    const float wxs = (lane & 16) ? wx1 : wx0;   // lane group picks its x-corner
    const float wav = a * wxs * wy0;
    const float wbv = a * wxs * wy1;

    const unsigned int* vb =
        (const unsigned int*)valueT + (size_t)nh * 11253 * 32;

    float acc0 = 0.f, acc1 = 0.f;
    const int srcb = g << 4;
#pragma unroll
    for (int pp = 0; pp < 16; pp++) {
        const int Wc = pp < 4 ? 92 : pp < 8 ? 46 : pp < 12 ? 23 : 12;
        const int src = pp + srcb;           // lane pp (g=0) or pp+16 (g=1)
        const int   i0 = __shfl(idx0v, src);
        const float w0 = __shfl(wav,   src);
        const float w1 = __shfl(wbv,   src);
        const int   i1 = i0 + Wc;            // y+1 row: stride known at compile time
        const unsigned d0 = vb[i0 * 32 + lane];   // lane>=32 reads pixel+1
        const unsigned d1 = vb[i1 * 32 + lane];
        acc0 = fmaf(w0, bflo(d0), acc0);
        acc1 = fmaf(w0, bfhi(d0), acc1);
        acc0 = fmaf(w1, bflo(d1), acc0);
        acc1 = fmaf(w1, bfhi(d1), acc1);
    }

    acc0 += __shfl(acc0, lane ^ 32);
    acc1 += __shfl(acc1, lane ^ 32);
    if (lane < 32) {
        const unsigned u = (unsigned)f2bf(acc0) | ((unsigned)f2bf(acc1) << 16);
        msout[(size_t)nq * 256 + h * 32 + (lane & 31)] = u;
    }
}

// ---------------------------------------------------------------------------
extern "C" void kernel_launch(void* const* d_in, const int* in_sizes, int n_in,
                              void* d_out, int out_size, void* d_ws, size_t ws_size,
                              hipStream_t stream) {
    (void)in_sizes; (void)n_in; (void)out_size; (void)ws_size;

    const float* query  = (const float*)d_in[0];
    const float* refp   = (const float*)d_in[1];
    const float* inpf   = (const float*)d_in[2];
    const float* W_off  = (const float*)d_in[5];
    const float* b_off  = (const float*)d_in[6];
    const float* W_attn = (const float*)d_in[7];
    const float* b_attn = (const float*)d_in[8];
    const float* W_val  = (const float*)d_in[9];
    const float* b_val  = (const float*)d_in[10];
    const float* W_out  = (const float*)d_in[11];
    const float* b_out  = (const float*)d_in[12];
    float* out = (float*)d_out;

    char* ws = (char*)d_ws;
    unsigned short* bf = (unsigned short*)ws;                    // 25,815,040 B
    unsigned short* inpfb   = bf;
    unsigned short* queryb  = bf + 11523072;
    unsigned short* W_offb  = bf + 12547072;   // [W_off;W_attn] = [384 x 256]
    unsigned short* W_valb  = bf + 12645376;
    unsigned short* W_outb  = bf + 12776448;
    unsigned short* valueT  = (unsigned short*)(ws + 25815040);  // 46,092,288 B
    float* fusedb = (float*)(ws + 71907328);                     //  6,144,000 B
    unsigned int* msoutu = (unsigned int*)(ws + 78051328);       //  4,096,000 B
    unsigned short* msoutb = (unsigned short*)msoutu;

    // 0. convert everything to bf16
    cvt_k<<<6303, 256, 0, stream>>>(inpf, query, W_off, W_attn, W_val, W_out, bf);
    // 1. merged: value projection (1408 blocks) + fused off/logits (96 blocks)
    gemm_bf16_tn<3><<<1504, 256, 0, stream>>>(
        inpfb, W_valb, queryb, W_offb, b_val, b_off, b_attn,
        valueT, fusedb, 45012, 512, 256);
    // 2. sampling (fused softmax), msout bf16
    sample_k<<<8000, 256, 0, stream>>>(valueT, refp, fusedb, msoutu);
    // 3. output projection
    gemm_bf16_tn<0><<<dim3(32, 2), 256, 0, stream>>>(
        msoutb, W_outb, nullptr, nullptr, b_out, nullptr, nullptr,
        out, nullptr, 4000, 256, 512);
}